// Round 7
// baseline (423.287 us; speedup 1.0000x reference)
//
#include <hip/hip_runtime.h>

// Problem constants
#define B_    64
#define C_    3
#define H_    384
#define W_    384
#define P_    16
#define E_    768
#define N_    576                 // patches per image
#define M_    (B_ * N_)           // 36864 total patches
#define K_    (C_ * P_ * P_)      // 768 reduction dim
#define HW_   (H_ * W_)
#define CHW_  (C_ * H_ * W_)

// GEMM tiling
#define BM    128
#define BN    128
#define BK    64
#define KITERS (K_ / BK)          // 12

typedef __attribute__((ext_vector_type(8))) short  short8;   // bf16x8 MFMA operand
typedef __attribute__((ext_vector_type(4))) float  f32x4;    // MFMA accumulator

// round-to-nearest-even f32 pair -> packed bf16x2 (low = a).
__device__ __forceinline__ unsigned int rnepair(float a, float b) {
    unsigned ua = __float_as_uint(a), ub = __float_as_uint(b);
    ua += 0x7FFFu + ((ua >> 16) & 1u);
    ub += 0x7FFFu + ((ub >> 16) & 1u);
    return (ua >> 16) | (ub & 0xFFFF0000u);
}

// 16B load with only 4B alignment guaranteed (xs is arbitrary).
__device__ __forceinline__ float4 ld16u(const float* p) {
    float4 v;
    __builtin_memcpy(&v, p, 16);
    return v;
}

// Phase 1: w [E][K] fp32 -> bf16 (B^T layout already)
__global__ __launch_bounds__(256)
void wconv_kernel(const float* __restrict__ w, unsigned short* __restrict__ Wb)
{
    const unsigned g = blockIdx.x * 256 + threadIdx.x;   // < E_*K_/4
    float4 f = ((const float4*)w)[g];
    uint2 pk;
    pk.x = rnepair(f.x, f.y);
    pk.y = rnepair(f.z, f.w);
    *(uint2*)(Wb + (size_t)g * 4) = pk;
}

// ---------------------------------------------------------------------------
// Fused gather+GEMM. Identical structure to round 5 (single-buffer 32 KB LDS,
// two raw s_barriers/iter with lgkmcnt(0) only — no vmcnt drain in loop,
// reg-staged A+B prefetch issued after barrier-1 and consumed at next pack,
// write+read XOR swizzle on both tiles: HW-verified SQ_LDS_BANK_CONFLICT=0).
// ONE change vs round 5: __launch_bounds__(256, 3). Round 5's allocator
// capped itself at 92 VGPR (occupancy heuristic) and spilled fr/bq -> ~210 MB
// scratch writes (WRITE_SIZE 320 MB vs 110 MB output). True demand ~155 VGPR;
// cap 3 waves/EU (~168 VGPR) fits spill-free, still 3 blocks/CU (12 waves).
// ---------------------------------------------------------------------------
__global__ __launch_bounds__(256, 3)
void fused_gemm(const float* __restrict__ x,
                const int*   __restrict__ ys,
                const int*   __restrict__ xs,
                const unsigned short* __restrict__ Wb,
                const float* __restrict__ bias,
                float*       __restrict__ out)
{
    __shared__ __align__(16) unsigned short Asm[BM * BK];   // 16 KB
    __shared__ __align__(16) unsigned short Bsm[BN * BK];   // 16 KB

    const int t    = threadIdx.x;
    const int wave = t >> 6;
    const int lane = t & 63;

    // XCD-aware swizzle: 1728 blocks = 8 xcd-groups x 36 m-tiles x 6 e-tiles.
    const int b   = blockIdx.x;
    const int xcd = b & 7;
    const int idx = b >> 3;              // 0..215
    const int mt  = xcd * 36 + idx / 6;  // m-tile 0..287
    const int et  = idx % 6;
    const int m0  = mt * BM;
    const int e0  = et * BN;

    // ---- A gather role: thread -> (patch p = t>>1, half h = t&1) ----
    const int p  = t >> 1;
    const int h  = t & 1;
    const int gp = m0 + p;
    const int bimg = gp / N_;
    const float* xrow = x + (size_t)bimg * CHW_ + ys[gp] * W_ + xs[gp] + 2 * h * W_;
    char* aw = (char*)Asm + p * 128;
    const int awz = (p & 7) << 4;
    const int h64 = h * 64;

    // ---- B staging role (reg-staged, swizzled ds_write) ----
    const int r8 = lane >> 3;                         // 0..7
    const unsigned short* Bg = Wb + (size_t)(e0 + wave * 32 + r8) * K_ + (lane & 7) * 8;
    char* bw = (char*)Bsm + (wave * 32 + r8) * 128 + (((lane & 7) * 16) ^ (r8 << 4));

    // ---- compute role ----
    const int wr   = (wave >> 1) * 64;
    const int wc   = (wave & 1) * 64;
    const int lm   = lane & 15;
    const int quad = lane >> 4;
    const char* Ard = (const char*)Asm + (wr + lm) * 128;
    const char* Brd = (const char*)Bsm + (wc + lm) * 128;
    const int rswz = (lm & 7) << 4;      // row&7 == lm&7 for all fragment rows

    f32x4 acc[4][4];
#pragma unroll
    for (int i = 0; i < 4; ++i)
#pragma unroll
        for (int j = 0; j < 4; ++j)
            acc[i][j] = (f32x4){0.f, 0.f, 0.f, 0.f};

    // prologue: issue tile-0 loads (A then B)
    float4 fr[8];
#pragma unroll
    for (int m = 0; m < 4; ++m) fr[m]     = ld16u(xrow + 4 * m);
#pragma unroll
    for (int m = 0; m < 4; ++m) fr[4 + m] = ld16u(xrow + W_ + 4 * m);
    uint4 bq[4];
#pragma unroll
    for (int i2 = 0; i2 < 4; ++i2)
        bq[i2] = *(const uint4*)(Bg + (size_t)i2 * 8 * K_);

#pragma unroll 1
    for (int it = 0; it < KITERS; ++it) {
        // pack A(t) + swizzled ds_write (compiler waits vmcnt for fr only)
#pragma unroll
        for (int j = 0; j < 4; ++j) {
            uint4 wv;
            wv.x = rnepair(fr[2*j].x,   fr[2*j].y);
            wv.y = rnepair(fr[2*j].z,   fr[2*j].w);
            wv.z = rnepair(fr[2*j+1].x, fr[2*j+1].y);
            wv.w = rnepair(fr[2*j+1].z, fr[2*j+1].w);
            *(uint4*)(aw + ((h64 + j * 16) ^ awz)) = wv;
        }
        // B(t) swizzled ds_write (waits vmcnt for bq)
#pragma unroll
        for (int i2 = 0; i2 < 4; ++i2)
            *(uint4*)(bw + i2 * (8 * 128)) = bq[i2];

        asm volatile("s_waitcnt lgkmcnt(0)" ::: "memory");
        __builtin_amdgcn_sched_barrier(0);           // rule-18 fence
        __builtin_amdgcn_s_barrier();                // barrier-1: tile t ready

        // issue tile t+1 loads into the SAME regs; consumed at next pack.
        // Latency budget: MFMA phase + barrier-2 + other-wave TLP.
        if (it + 1 < KITERS) {
            const int itn = it + 1;
            const float* rp = xrow + (itn >> 2) * HW_ + ((itn & 3) << 2) * W_;
#pragma unroll
            for (int m = 0; m < 4; ++m) fr[m]     = ld16u(rp + 4 * m);
#pragma unroll
            for (int m = 0; m < 4; ++m) fr[4 + m] = ld16u(rp + W_ + 4 * m);
            const unsigned short* bgn = Bg + itn * BK;
#pragma unroll
            for (int i2 = 0; i2 < 4; ++i2)
                bq[i2] = *(const uint4*)(bgn + (size_t)i2 * 8 * K_);
        }

        // MFMA over tile t (swizzled, conflict-free reads)
#pragma unroll
        for (int s = 0; s < 2; ++s) {
            short8 af[4], bfr[4];
#pragma unroll
            for (int i = 0; i < 4; ++i)
                af[i]  = *(const short8*)(Ard + i * (16 * 128)
                                              + ((s * 64 + quad * 16) ^ rswz));
#pragma unroll
            for (int j = 0; j < 4; ++j)
                bfr[j] = *(const short8*)(Brd + j * (16 * 128)
                                              + ((s * 64 + quad * 16) ^ rswz));
#pragma unroll
            for (int i = 0; i < 4; ++i)
#pragma unroll
                for (int j = 0; j < 4; ++j)
                    acc[i][j] = __builtin_amdgcn_mfma_f32_16x16x32_bf16(af[i], bfr[j], acc[i][j], 0, 0, 0);
        }

        // barrier-2: reads of tile t done (each wave's lgkm waits precede its
        // MFMAs) -> safe for next iteration's LDS writes.
        asm volatile("s_waitcnt lgkmcnt(0)" ::: "memory");
        __builtin_amdgcn_s_barrier();
    }

    // epilogue: C/D layout col=lane&15, row=quad*4+reg (m89-verified)
    float bv[4];
#pragma unroll
    for (int j = 0; j < 4; ++j) bv[j] = bias[e0 + wc + j * 16 + lm];

#pragma unroll
    for (int i = 0; i < 4; ++i) {
#pragma unroll
        for (int j = 0; j < 4; ++j) {
            const int eo = e0 + wc + j * 16 + lm;
#pragma unroll
            for (int r = 0; r < 4; ++r) {
                const int mo = m0 + wr + i * 16 + quad * 4 + r;
                out[(size_t)mo * E_ + eo] = acc[i][j][r] + bv[j];
            }
        }
    }
}

__global__ void pos_kernel(const int* __restrict__ ys, const int* __restrict__ xs,
                           float* __restrict__ outp)
{
    int i = blockIdx.x * blockDim.x + threadIdx.x;
    if (i < M_) {
        outp[2 * i]     = (float)ys[i];
        outp[2 * i + 1] = (float)xs[i];
    }
}

extern "C" void kernel_launch(void* const* d_in, const int* in_sizes, int n_in,
                              void* d_out, int out_size, void* d_ws, size_t ws_size,
                              hipStream_t stream)
{
    const float* x    = (const float*)d_in[0];
    const int*   ys   = (const int*)d_in[1];
    const int*   xs   = (const int*)d_in[2];
    const float* w    = (const float*)d_in[3];
    const float* bias = (const float*)d_in[4];
    float* out = (float*)d_out;

    unsigned short* Wb = (unsigned short*)d_ws;

    wconv_kernel<<<(E_ * K_ / 4) / 256, 256, 0, stream>>>(w, Wb);

    fused_gemm<<<(M_ / BM) * (E_ / BN), 256, 0, stream>>>(x, ys, xs, Wb, bias, out);

    float* outp = out + (size_t)M_ * E_;
    pos_kernel<<<(M_ + 255) / 256, 256, 0, stream>>>(ys, xs, outp);
}

// Round 8
// 285.394 us; speedup vs baseline: 1.4832x; 1.4832x over previous
//
#include <hip/hip_runtime.h>

// Problem constants
#define B_    64
#define C_    3
#define H_    384
#define W_    384
#define P_    16
#define E_    768
#define N_    576                 // patches per image
#define M_    (B_ * N_)           // 36864 total patches
#define K_    (C_ * P_ * P_)      // 768 reduction dim

// GEMM tiling
#define BM    128
#define BN    128
#define BK    64
#define KITERS (K_ / BK)          // 12
#define TILE_ELEMS (BM * BK)      // 8192 bf16 = 16 KB

typedef __attribute__((ext_vector_type(8))) short  short8;   // bf16x8 MFMA operand
typedef __attribute__((ext_vector_type(4))) float  f32x4;    // MFMA accumulator

// round-to-nearest-even f32 -> bf16 bits
__device__ __forceinline__ unsigned short f2bf(float f) {
    unsigned int u = __float_as_uint(f);
    u += 0x7FFFu + ((u >> 16) & 1u);
    return (unsigned short)(u >> 16);
}

// async global->LDS, 16B per lane (global_load_lds_dwordx4)
__device__ __forceinline__ void gload_lds16(const void* g, void* l) {
    __builtin_amdgcn_global_load_lds(
        (const __attribute__((address_space(1))) unsigned int*)g,
        (__attribute__((address_space(3))) unsigned int*)l,
        16, 0, 0);
}

// ---------------------------------------------------------------------------
// Phase 1: gather patches -> contiguous bf16 A[M][768] (R0-proven, 45 us).
// ---------------------------------------------------------------------------
__global__ __launch_bounds__(256)
void gather_kernel(const float* __restrict__ x,
                   const int*   __restrict__ ys,
                   const int*   __restrict__ xs,
                   unsigned short* __restrict__ Abf)
{
    const unsigned g = blockIdx.x * 256 + threadIdx.x;   // < M_*192
    const unsigned patch = g / 192u;
    const unsigned r  = g - patch * 192u;                // 0..191
    const unsigned c  = r >> 6;                          // channel 0..2
    const unsigned r2 = r & 63u;
    const unsigned py = r2 >> 2;                         // row in patch 0..15
    const unsigned q  = r2 & 3u;                         // 4-float quarter

    const unsigned bimg = patch / (unsigned)N_;
    const int y  = ys[patch];
    const int xx = xs[patch];

    const float* src = x + (size_t)bimg * (C_ * H_ * W_)
                         + (size_t)c * (H_ * W_)
                         + (size_t)(y + py) * W_ + xx + q * 4;

    uint2 pk;
    pk.x = (unsigned)f2bf(src[0]) | ((unsigned)f2bf(src[1]) << 16);
    pk.y = (unsigned)f2bf(src[2]) | ((unsigned)f2bf(src[3]) << 16);
    *(uint2*)(Abf + (size_t)g * 4) = pk;
}

// Phase 1b: w [E][K] fp32 -> bf16 (B^T layout already)
__global__ __launch_bounds__(256)
void wconv_kernel(const float* __restrict__ w, unsigned short* __restrict__ Wb)
{
    const unsigned g = blockIdx.x * 256 + threadIdx.x;   // < E_*K_/4
    float4 f = ((const float4*)w)[g];
    uint2 pk;
    pk.x = (unsigned)f2bf(f.x) | ((unsigned)f2bf(f.y) << 16);
    pk.y = (unsigned)f2bf(f.z) | ((unsigned)f2bf(f.w) << 16);
    *(uint2*)(Wb + (size_t)g * 4) = pk;
}

// ---------------------------------------------------------------------------
// Phase 2: GEMM with T4 counted-vmcnt double-buffer pipeline.
//   prologue: STAGE(0->buf0), STAGE(1->buf1)      (8 gload_lds each / wave)
//   iter t:   vmcnt(8)  [tile t landed; tile t+1 stays in flight]
//             barrier; MFMA(t) from buf[t&1]; lgkmcnt(0); barrier;
//             STAGE(t+2 -> buf[t&1])
//   last iter: vmcnt(0) (still 1.5 iters after issue -> hidden).
// No vmcnt(0)-against-fresh-loads anywhere: issue->consume = 2 iterations.
// LDS conflict fix via pre-swizzled SOURCE (m173): the gload_lds global addr
// XORs chunk bits with (row&7)<<3 elems (stays in the same 128B line ->
// coalescing intact); LDS dest stays linear; frag reads apply the same XOR.
// ---------------------------------------------------------------------------
__global__ __launch_bounds__(256)
void gemm_bf16(const unsigned short* __restrict__ A,
               const unsigned short* __restrict__ Wb,
               const float* __restrict__ bias,
               float*       __restrict__ out)
{
    __shared__ __align__(16) unsigned short Asm[2][TILE_ELEMS];  // 32 KB
    __shared__ __align__(16) unsigned short Bsm[2][TILE_ELEMS];  // 32 KB

    const int t    = threadIdx.x;
    const int wave = t >> 6;
    const int lane = t & 63;

    // XCD-aware swizzle: 1728 blocks = 8 xcd-groups x 36 m-tiles x 6 e-tiles
    const int b   = blockIdx.x;
    const int xcd = b & 7;
    const int idx = b >> 3;              // 0..215
    const int mt  = xcd * 36 + idx / 6;  // m-tile 0..287
    const int et  = idx % 6;
    const int m0  = mt * BM;
    const int e0  = et * BN;

    // staging: wave stages rows [wave*32, wave*32+32), 8 rows/instruction.
    // row = wave*32 + inst*8 + r8  ->  row&7 == r8 always.
    const int r8 = lane >> 3;            // 0..7
    const int c8 = (lane & 7) * 8;       // linear chunk (elems)
    const int cx = c8 ^ (r8 << 3);       // source-swizzled chunk (elems)
    const unsigned short* Ag = A  + (size_t)(m0 + wave * 32 + r8) * K_ + cx;
    const unsigned short* Bg = Wb + (size_t)(e0 + wave * 32 + r8) * K_ + cx;
    unsigned short* Al = &Asm[0][(wave * 32 + r8) * BK + c8];  // linear dest
    unsigned short* Bl = &Bsm[0][(wave * 32 + r8) * BK + c8];

    // compute roles
    const int wr   = (wave >> 1) * 64;
    const int wc   = (wave & 1) * 64;
    const int lm   = lane & 15;
    const int quad = lane >> 4;
    const int rsw  = (lm & 7) << 3;      // read XOR (elems); row&7 == lm&7

    f32x4 acc[4][4];
#pragma unroll
    for (int i = 0; i < 4; ++i)
#pragma unroll
        for (int j = 0; j < 4; ++j)
            acc[i][j] = (f32x4){0.f, 0.f, 0.f, 0.f};

    // bias preloaded BEFORE staging so it never perturbs vmcnt counting
    float bv[4];
#pragma unroll
    for (int j = 0; j < 4; ++j) bv[j] = bias[e0 + wc + j * 16 + lm];

#define STAGE(tt, bsel)                                                       \
    do {                                                                      \
        const int _ko = (tt) * BK;                                            \
        const int _lo = (bsel) * TILE_ELEMS;                                  \
        _Pragma("unroll")                                                     \
        for (int _i = 0; _i < 4; ++_i) {                                      \
            gload_lds16(Ag + _ko + (size_t)(_i * 8) * K_, Al + _lo + _i * 8 * BK); \
            gload_lds16(Bg + _ko + (size_t)(_i * 8) * K_, Bl + _lo + _i * 8 * BK); \
        }                                                                     \
    } while (0)

    // prologue: two tiles in flight
    STAGE(0, 0);
    STAGE(1, 1);

#pragma unroll 1
    for (int it = 0; it < KITERS; ++it) {
        if (it < KITERS - 1)
            asm volatile("s_waitcnt vmcnt(8)" ::: "memory");   // tile it done
        else
            asm volatile("s_waitcnt vmcnt(0)" ::: "memory");   // final drain
        __builtin_amdgcn_sched_barrier(0);
        __builtin_amdgcn_s_barrier();            // tile it visible to all
        __builtin_amdgcn_sched_barrier(0);

        const int bo = (it & 1) * TILE_ELEMS;
#pragma unroll
        for (int s = 0; s < 2; ++s) {            // two K=32 sub-steps
            short8 af[4], bfr[4];
            const int eo2 = (s * 32 + quad * 8) ^ rsw;   // swizzled elem off
#pragma unroll
            for (int i = 0; i < 4; ++i)
                af[i]  = *(const short8*)&Asm[0][bo + (wr + i * 16 + lm) * BK + eo2];
#pragma unroll
            for (int j = 0; j < 4; ++j)
                bfr[j] = *(const short8*)&Bsm[0][bo + (wc + j * 16 + lm) * BK + eo2];
#pragma unroll
            for (int i = 0; i < 4; ++i)
#pragma unroll
                for (int j = 0; j < 4; ++j)
                    acc[i][j] = __builtin_amdgcn_mfma_f32_16x16x32_bf16(af[i], bfr[j], acc[i][j], 0, 0, 0);
        }

        asm volatile("s_waitcnt lgkmcnt(0)" ::: "memory");  // my reads done
        __builtin_amdgcn_sched_barrier(0);
        __builtin_amdgcn_s_barrier();            // everyone's reads done
        __builtin_amdgcn_sched_barrier(0);

        if (it + 2 < KITERS)
            STAGE(it + 2, it & 1);               // refill the freed buffer
    }
#undef STAGE

    // epilogue: C/D layout col=lane&15, row=quad*4+reg (m89-verified)
#pragma unroll
    for (int i = 0; i < 4; ++i) {
#pragma unroll
        for (int j = 0; j < 4; ++j) {
            const int eo = e0 + wc + j * 16 + lm;
#pragma unroll
            for (int r = 0; r < 4; ++r) {
                const int mo = m0 + wr + i * 16 + quad * 4 + r;
                out[(size_t)mo * E_ + eo] = acc[i][j][r] + bv[j];
            }
        }
    }
}

__global__ void pos_kernel(const int* __restrict__ ys, const int* __restrict__ xs,
                           float* __restrict__ outp)
{
    int i = blockIdx.x * blockDim.x + threadIdx.x;
    if (i < M_) {
        outp[2 * i]     = (float)ys[i];
        outp[2 * i + 1] = (float)xs[i];
    }
}

extern "C" void kernel_launch(void* const* d_in, const int* in_sizes, int n_in,
                              void* d_out, int out_size, void* d_ws, size_t ws_size,
                              hipStream_t stream)
{
    const float* x    = (const float*)d_in[0];
    const int*   ys   = (const int*)d_in[1];
    const int*   xs   = (const int*)d_in[2];
    const float* w    = (const float*)d_in[3];
    const float* bias = (const float*)d_in[4];
    float* out = (float*)d_out;

    // workspace layout: A_bf16 [M][768] then W_bf16 [E][768]
    unsigned short* Abf = (unsigned short*)d_ws;
    unsigned short* Wb  = Abf + (size_t)M_ * K_;

    gather_kernel<<<(M_ * 192) / 256, 256, 0, stream>>>(x, ys, xs, Abf);
    wconv_kernel<<<(E_ * K_ / 4) / 256, 256, 0, stream>>>(w, Wb);

    gemm_bf16<<<(M_ / BM) * (E_ / BN), 256, 0, stream>>>(Abf, Wb, bias, out);

    float* outp = out + (size_t)M_ * E_;
    pos_kernel<<<(M_ + 255) / 256, 256, 0, stream>>>(ys, xs, outp);
}

// Round 9
// 277.214 us; speedup vs baseline: 1.5269x; 1.0295x over previous
//
#include <hip/hip_runtime.h>

// Problem constants
#define B_    64
#define C_    3
#define H_    384
#define W_    384
#define P_    16
#define E_    768
#define N_    576                 // patches per image
#define M_    (B_ * N_)           // 36864 total patches
#define K_    (C_ * P_ * P_)      // 768 reduction dim

// GEMM tiling
#define BM    128
#define BN    128
#define BK    64
#define KITERS (K_ / BK)          // 12
#define TILE_ELEMS (BM * BK)      // 8192 bf16 = 16 KB

// prep kernel partition
#define GATHER_TOTAL  (M_ * 192)               // 7,077,888 work items
#define GATHER_BLOCKS 2048                     // grid-stride (G11)
#define WCONV_BLOCKS  (E_ * K_ / 4 / 256)      // 576
#define POS_BLOCKS    (M_ / 256)               // 144
#define PREP_BLOCKS   (GATHER_BLOCKS + WCONV_BLOCKS + POS_BLOCKS)

typedef __attribute__((ext_vector_type(8))) short  short8;   // bf16x8 MFMA operand
typedef __attribute__((ext_vector_type(4))) float  f32x4;    // MFMA accumulator

// round-to-nearest-even f32 -> bf16 bits
__device__ __forceinline__ unsigned short f2bf(float f) {
    unsigned int u = __float_as_uint(f);
    u += 0x7FFFu + ((u >> 16) & 1u);
    return (unsigned short)(u >> 16);
}

// async global->LDS, 16B per lane (global_load_lds_dwordx4)
__device__ __forceinline__ void gload_lds16(const void* g, void* l) {
    __builtin_amdgcn_global_load_lds(
        (const __attribute__((address_space(1))) unsigned int*)g,
        (__attribute__((address_space(3))) unsigned int*)l,
        16, 0, 0);
}

// ---------------------------------------------------------------------------
// Phase 1 (single launch): block-range-partitioned prep.
//   blocks [0, 2048)           : gather patches -> bf16 A[M][768], grid-stride
//   blocks [2048, 2048+576)    : w fp32 -> bf16 Wb (B^T layout)
//   blocks [2624, 2624+144)    : patch positions -> out tail
// Branches are wave-uniform (per-block), three independent memory streams.
// ---------------------------------------------------------------------------
__global__ __launch_bounds__(256)
void prep_kernel(const float* __restrict__ x,
                 const int*   __restrict__ ys,
                 const int*   __restrict__ xs,
                 const float* __restrict__ w,
                 unsigned short* __restrict__ Abf,
                 unsigned short* __restrict__ Wb,
                 float*       __restrict__ outp)
{
    const int blk = blockIdx.x;

    if (blk < GATHER_BLOCKS) {
        // grid-stride gather: ~13.5 iters/thread, 16B read + 8B write each
        for (unsigned g = blk * 256u + threadIdx.x; g < (unsigned)GATHER_TOTAL;
             g += GATHER_BLOCKS * 256u) {
            const unsigned patch = g / 192u;
            const unsigned r  = g - patch * 192u;            // 0..191
            const unsigned c  = r >> 6;                      // channel 0..2
            const unsigned r2 = r & 63u;
            const unsigned py = r2 >> 2;                     // row in patch
            const unsigned q  = r2 & 3u;                     // 4-float quarter

            const unsigned bimg = patch / (unsigned)N_;
            const int y  = ys[patch];
            const int xx = xs[patch];

            const float* src = x + (size_t)bimg * (C_ * H_ * W_)
                                 + (size_t)c * (H_ * W_)
                                 + (size_t)(y + py) * W_ + xx + q * 4;

            uint2 pk;
            pk.x = (unsigned)f2bf(src[0]) | ((unsigned)f2bf(src[1]) << 16);
            pk.y = (unsigned)f2bf(src[2]) | ((unsigned)f2bf(src[3]) << 16);
            *(uint2*)(Abf + (size_t)g * 4) = pk;
        }
    } else if (blk < GATHER_BLOCKS + WCONV_BLOCKS) {
        const unsigned g = (blk - GATHER_BLOCKS) * 256u + threadIdx.x;
        float4 f = ((const float4*)w)[g];
        uint2 pk;
        pk.x = (unsigned)f2bf(f.x) | ((unsigned)f2bf(f.y) << 16);
        pk.y = (unsigned)f2bf(f.z) | ((unsigned)f2bf(f.w) << 16);
        *(uint2*)(Wb + (size_t)g * 4) = pk;
    } else {
        const int i = (blk - GATHER_BLOCKS - WCONV_BLOCKS) * 256 + threadIdx.x;
        // 144*256 == M_ exactly, no bound check needed
        outp[2 * i]     = (float)ys[i];
        outp[2 * i + 1] = (float)xs[i];
    }
}

// ---------------------------------------------------------------------------
// Phase 2: GEMM with T4 counted-vmcnt double-buffer pipeline (FROZEN from
// round 8 — passed refcheck, dropped below the 75 us fill dispatches).
//   prologue: STAGE(0->buf0), STAGE(1->buf1)      (8 gload_lds each / wave)
//   iter t:   vmcnt(8)  [tile t landed; tile t+1 stays in flight]
//             barrier; MFMA(t) from buf[t&1]; lgkmcnt(0); barrier;
//             STAGE(t+2 -> buf[t&1])
// No vmcnt(0)-against-fresh-loads anywhere: issue->consume = 2 iterations.
// LDS conflict fix via pre-swizzled SOURCE (m173): gload_lds global addr XORs
// chunk with (row&7)<<3 elems (same 128B line -> coalescing intact); LDS dest
// linear; frag reads apply the matching XOR.
// ---------------------------------------------------------------------------
__global__ __launch_bounds__(256)
void gemm_bf16(const unsigned short* __restrict__ A,
               const unsigned short* __restrict__ Wb,
               const float* __restrict__ bias,
               float*       __restrict__ out)
{
    __shared__ __align__(16) unsigned short Asm[2][TILE_ELEMS];  // 32 KB
    __shared__ __align__(16) unsigned short Bsm[2][TILE_ELEMS];  // 32 KB

    const int t    = threadIdx.x;
    const int wave = t >> 6;
    const int lane = t & 63;

    // XCD-aware swizzle: 1728 blocks = 8 xcd-groups x 36 m-tiles x 6 e-tiles
    const int b   = blockIdx.x;
    const int xcd = b & 7;
    const int idx = b >> 3;              // 0..215
    const int mt  = xcd * 36 + idx / 6;  // m-tile 0..287
    const int et  = idx % 6;
    const int m0  = mt * BM;
    const int e0  = et * BN;

    // staging: wave stages rows [wave*32, wave*32+32), 8 rows/instruction.
    // row = wave*32 + inst*8 + r8  ->  row&7 == r8 always.
    const int r8 = lane >> 3;            // 0..7
    const int c8 = (lane & 7) * 8;       // linear chunk (elems)
    const int cx = c8 ^ (r8 << 3);       // source-swizzled chunk (elems)
    const unsigned short* Ag = A  + (size_t)(m0 + wave * 32 + r8) * K_ + cx;
    const unsigned short* Bg = Wb + (size_t)(e0 + wave * 32 + r8) * K_ + cx;
    unsigned short* Al = &Asm[0][(wave * 32 + r8) * BK + c8];  // linear dest
    unsigned short* Bl = &Bsm[0][(wave * 32 + r8) * BK + c8];

    // compute roles
    const int wr   = (wave >> 1) * 64;
    const int wc   = (wave & 1) * 64;
    const int lm   = lane & 15;
    const int quad = lane >> 4;
    const int rsw  = (lm & 7) << 3;      // read XOR (elems); row&7 == lm&7

    f32x4 acc[4][4];
#pragma unroll
    for (int i = 0; i < 4; ++i)
#pragma unroll
        for (int j = 0; j < 4; ++j)
            acc[i][j] = (f32x4){0.f, 0.f, 0.f, 0.f};

    // bias preloaded BEFORE staging so it never perturbs vmcnt counting
    float bv[4];
#pragma unroll
    for (int j = 0; j < 4; ++j) bv[j] = bias[e0 + wc + j * 16 + lm];

#define STAGE(tt, bsel)                                                       \
    do {                                                                      \
        const int _ko = (tt) * BK;                                            \
        const int _lo = (bsel) * TILE_ELEMS;                                  \
        _Pragma("unroll")                                                     \
        for (int _i = 0; _i < 4; ++_i) {                                      \
            gload_lds16(Ag + _ko + (size_t)(_i * 8) * K_, Al + _lo + _i * 8 * BK); \
            gload_lds16(Bg + _ko + (size_t)(_i * 8) * K_, Bl + _lo + _i * 8 * BK); \
        }                                                                     \
    } while (0)

    // prologue: two tiles in flight
    STAGE(0, 0);
    STAGE(1, 1);

#pragma unroll 1
    for (int it = 0; it < KITERS; ++it) {
        if (it < KITERS - 1)
            asm volatile("s_waitcnt vmcnt(8)" ::: "memory");   // tile it done
        else
            asm volatile("s_waitcnt vmcnt(0)" ::: "memory");   // final drain
        __builtin_amdgcn_sched_barrier(0);
        __builtin_amdgcn_s_barrier();            // tile it visible to all
        __builtin_amdgcn_sched_barrier(0);

        const int bo = (it & 1) * TILE_ELEMS;
#pragma unroll
        for (int s = 0; s < 2; ++s) {            // two K=32 sub-steps
            short8 af[4], bfr[4];
            const int eo2 = (s * 32 + quad * 8) ^ rsw;   // swizzled elem off
#pragma unroll
            for (int i = 0; i < 4; ++i)
                af[i]  = *(const short8*)&Asm[0][bo + (wr + i * 16 + lm) * BK + eo2];
#pragma unroll
            for (int j = 0; j < 4; ++j)
                bfr[j] = *(const short8*)&Bsm[0][bo + (wc + j * 16 + lm) * BK + eo2];
#pragma unroll
            for (int i = 0; i < 4; ++i)
#pragma unroll
                for (int j = 0; j < 4; ++j)
                    acc[i][j] = __builtin_amdgcn_mfma_f32_16x16x32_bf16(af[i], bfr[j], acc[i][j], 0, 0, 0);
        }

        asm volatile("s_waitcnt lgkmcnt(0)" ::: "memory");  // my reads done
        __builtin_amdgcn_sched_barrier(0);
        __builtin_amdgcn_s_barrier();            // everyone's reads done
        __builtin_amdgcn_sched_barrier(0);

        if (it + 2 < KITERS)
            STAGE(it + 2, it & 1);               // refill the freed buffer
    }
#undef STAGE

    // epilogue: C/D layout col=lane&15, row=quad*4+reg (m89-verified)
#pragma unroll
    for (int i = 0; i < 4; ++i) {
#pragma unroll
        for (int j = 0; j < 4; ++j) {
            const int eo = e0 + wc + j * 16 + lm;
#pragma unroll
            for (int r = 0; r < 4; ++r) {
                const int mo = m0 + wr + i * 16 + quad * 4 + r;
                out[(size_t)mo * E_ + eo] = acc[i][j][r] + bv[j];
            }
        }
    }
}

extern "C" void kernel_launch(void* const* d_in, const int* in_sizes, int n_in,
                              void* d_out, int out_size, void* d_ws, size_t ws_size,
                              hipStream_t stream)
{
    const float* x    = (const float*)d_in[0];
    const int*   ys   = (const int*)d_in[1];
    const int*   xs   = (const int*)d_in[2];
    const float* w    = (const float*)d_in[3];
    const float* bias = (const float*)d_in[4];
    float* out = (float*)d_out;

    // workspace layout: A_bf16 [M][768] then W_bf16 [E][768]
    unsigned short* Abf = (unsigned short*)d_ws;
    unsigned short* Wb  = Abf + (size_t)M_ * K_;
    float* outp = out + (size_t)M_ * E_;

    prep_kernel<<<PREP_BLOCKS, 256, 0, stream>>>(x, ys, xs, w, Abf, Wb, outp);

    gemm_bf16<<<(M_ / BM) * (E_ / BN), 256, 0, stream>>>(Abf, Wb, bias, out);
}